// Round 2
// baseline (2583.157 us; speedup 1.0000x reference)
//
#include <hip/hip_runtime.h>
#include <hip/hip_cooperative_groups.h>
#include <cstddef>

#define WEMB_K 300

namespace cg = cooperative_groups;

typedef short bf16x8 __attribute__((ext_vector_type(8)));
typedef float f32x4 __attribute__((ext_vector_type(4)));

__device__ __forceinline__ float sigm(float x) { return 1.f / (1.f + expf(-x)); }

// f32 -> bf16 (round to nearest even)
__device__ __forceinline__ unsigned short f2bf(float f) {
    union { float f; unsigned u; } v; v.f = f;
    return (unsigned short)((v.u + 0x7FFFu + ((v.u >> 16) & 1u)) >> 16);
}

// ============================================================================
// proj_mfma: out[M,2048] = cvt_bf16(A[M,K]) @ [Wf|Wb]^T + [bf|bb]   (f32 out)
// A rows gathered via ids0/ids1 (embedding lookup) or dense (ids0==null).
// Tile 128 rows x 64 cols, K-chunks of 32, MFMA 16x16x32 bf16.
// Wave w: row-tiles {2w,2w+1}, col-tiles 0..3.
// ============================================================================
__global__ __launch_bounds__(256) void proj_mfma(
    const float* __restrict__ A,
    const int* __restrict__ ids0, const int* __restrict__ ids1, int idsSplit,
    int M, int K,
    const float* __restrict__ Wf, const float* __restrict__ Wb,
    const float* __restrict__ bf_, const float* __restrict__ bb_,
    float* __restrict__ out)
{
    __shared__ unsigned int As[128][20];   // bf16 pairs, pitch 40 bf16
    __shared__ unsigned int Ws[64][20];
    const int tid  = threadIdx.x;
    const int lane = tid & 63;
    const int w    = tid >> 6;
    const int n    = lane & 15;
    const int quad = lane >> 4;
    const int bm   = blockIdx.x * 128;
    const int by   = blockIdx.y;                   // 0..31 (64-col tiles)
    const float* W    = (by < 16) ? Wf : Wb;
    const float* bias = (by < 16) ? bf_ : bb_;
    const int wcol0   = (by < 16) ? by * 64 : (by - 16) * 64;

    // A staging assignment: row = bm + tid>>1, k-base = (tid&1)*16
    const int arowL = tid >> 1;
    const int arow  = bm + arowL;
    const bool av   = (arow < M);
    const float* aPtr;
    if (ids0) {
        int id = 0;
        if (arow < idsSplit) id = ids0[arow];
        else if (arow < M)   id = ids1[arow - idsSplit];
        aPtr = A + (size_t)id * K;
    } else {
        aPtr = A + (size_t)(av ? arow : 0) * K;
    }
    const int akb = (tid & 1) * 16;
    // W staging assignment: col = tid>>2, k-base = (tid&3)*8
    const int wc  = tid >> 2;
    const int wkb = (tid & 3) * 8;
    const float* wPtr = W + (size_t)(wcol0 + wc) * K;

    f32x4 acc[2][4];
#pragma unroll
    for (int rt = 0; rt < 2; rt++)
#pragma unroll
        for (int ct = 0; ct < 4; ct++) acc[rt][ct] = (f32x4){0.f, 0.f, 0.f, 0.f};

    const int ksteps = (K + 31) / 32;
    for (int kc = 0; kc < ksteps; kc++) {
        const int k0 = kc * 32;
        {
            unsigned int u[8];
#pragma unroll
            for (int i = 0; i < 8; i++) {
                int k = k0 + akb + i * 2;
                float f0 = (av && k     < K) ? aPtr[k]     : 0.f;
                float f1 = (av && k + 1 < K) ? aPtr[k + 1] : 0.f;
                u[i] = (unsigned)f2bf(f0) | ((unsigned)f2bf(f1) << 16);
            }
#pragma unroll
            for (int i = 0; i < 8; i++) As[arowL][akb / 2 + i] = u[i];
        }
        {
#pragma unroll
            for (int i = 0; i < 4; i++) {
                int k = k0 + wkb + i * 2;
                float f0 = (k     < K) ? wPtr[k]     : 0.f;
                float f1 = (k + 1 < K) ? wPtr[k + 1] : 0.f;
                Ws[wc][wkb / 2 + i] = (unsigned)f2bf(f0) | ((unsigned)f2bf(f1) << 16);
            }
        }
        __syncthreads();
        bf16x8 Aq[2], Bq[4];
#pragma unroll
        for (int rt = 0; rt < 2; rt++)
            Aq[rt] = *(const bf16x8*)&As[(w * 2 + rt) * 16 + n][quad * 4];
#pragma unroll
        for (int ct = 0; ct < 4; ct++)
            Bq[ct] = *(const bf16x8*)&Ws[ct * 16 + n][quad * 4];
#pragma unroll
        for (int rt = 0; rt < 2; rt++)
#pragma unroll
            for (int ct = 0; ct < 4; ct++)
                acc[rt][ct] = __builtin_amdgcn_mfma_f32_16x16x32_bf16(
                    Aq[rt], Bq[ct], acc[rt][ct], 0, 0, 0);
        __syncthreads();
    }

#pragma unroll
    for (int rt = 0; rt < 2; rt++) {
        const int rbase = bm + (w * 2 + rt) * 16 + quad * 4;
#pragma unroll
        for (int ct = 0; ct < 4; ct++) {
            const int col  = wcol0 + ct * 16 + n;           // within 0..1023
            const int gcol = (by < 16) ? col : 1024 + col;  // within 0..2047
            const float bv = bias[col];
#pragma unroll
            for (int r = 0; r < 4; r++) {
                int row = rbase + r;
                if (row < M) out[(size_t)row * 2048 + gcol] = acc[rt][ct][r] + bv;
            }
        }
    }
}

// ============================================================================
// lstm_sen: persistent cooperative BiLSTM over sentence words + titles.
// Rows (seq-dirs): 0..639 sen-fwd | 640..1279 sen-bwd | 1280..1343 head-fwd |
// 1344..1407 head-bwd.  Grid (22,16): block = 64 rows x 16 units (64 gate
// cols, local col c = unit*4 + gate).  Whh bf16 B-frags in registers; h
// ping-pongs bf16 through global; c persists in LDS.  One grid.sync per step.
// ============================================================================
__global__ __launch_bounds__(256, 2) void lstm_sen(
    const float* __restrict__ xw, const float* __restrict__ xw_head,
    const float* __restrict__ whh_f, const float* __restrict__ whh_b,
    unsigned short* hbA, unsigned short* hbB,
    float* __restrict__ sentences, float* __restrict__ headings)
{
    const int tid  = threadIdx.x;
    const int lane = tid & 63;
    const int w    = tid >> 6;
    const int n    = lane & 15;
    const int quad = lane >> 4;
    const int bx   = blockIdx.x;         // 0..21
    const int by   = blockIdx.y;         // 0..15
    const int r0   = bx * 64;
    const int u0   = by * 16;
    const bool bwd  = (bx >= 10 && bx < 20) || (bx == 21);
    const bool head = (bx >= 20);
    const float* whh = bwd ? whh_b : whh_f;

    __shared__ float G[64][65];
    __shared__ float cbuf[64][16];

    // one-time: weights into registers (B-frag: lane holds B[k=quad*8+j][16ct+n])
    bf16x8 Bf[4][8];
#pragma unroll
    for (int ct = 0; ct < 4; ct++) {
        const int c    = ct * 16 + n;
        const int grow = (c & 3) * 256 + u0 + (c >> 2);   // gate*256 + unit
        const float* wr = whh + (size_t)grow * 256;
#pragma unroll
        for (int ks = 0; ks < 8; ks++) {
            union { bf16x8 v; short s[8]; } tmp;
            const float* p = wr + ks * 32 + quad * 8;
#pragma unroll
            for (int j = 0; j < 8; j++) tmp.s[j] = (short)f2bf(p[j]);
            Bf[ct][ks] = tmp.v;
        }
    }

    cg::grid_group grid = cg::this_grid();

    for (int t = 0; t < 30; t++) {
        const unsigned short* hp = (t & 1) ? hbB : hbA;
        unsigned short*       hq = (t & 1) ? hbA : hbB;
        const bool active = !(head && t >= 15);
        if (active) {
            const unsigned short* hrow = hp + (size_t)(r0 + w * 16 + n) * 256;
            bf16x8 Af[8];
#pragma unroll
            for (int ks = 0; ks < 8; ks++)
                Af[ks] = *(const bf16x8*)(hrow + ks * 32 + quad * 8);
            f32x4 acc[4];
#pragma unroll
            for (int ct = 0; ct < 4; ct++) {
                acc[ct] = (f32x4){0.f, 0.f, 0.f, 0.f};
#pragma unroll
                for (int ks = 0; ks < 8; ks++)
                    acc[ct] = __builtin_amdgcn_mfma_f32_16x16x32_bf16(
                        Af[ks], Bf[ct][ks], acc[ct], 0, 0, 0);
            }
#pragma unroll
            for (int ct = 0; ct < 4; ct++)
#pragma unroll
                for (int r = 0; r < 4; r++)
                    G[w * 16 + quad * 4 + r][ct * 16 + n] = acc[ct][r];
        }
        __syncthreads();
        if (active) {
#pragma unroll
            for (int pp = 0; pp < 4; pp++) {
                const int idx = tid + pp * 256;
                const int rr = idx >> 4, uu = idx & 15;
                const int grow = r0 + rr;
                const int j = u0 + uu;
                const float* xp;
                int cb;
                float* fdst = nullptr;
                if (grow < 640) {
                    xp = xw + (size_t)(grow * 30 + t) * 2048; cb = j;
                    if (t == 29) fdst = sentences + (size_t)grow * 512 + j;
                } else if (grow < 1280) {
                    int s = grow - 640;
                    xp = xw + (size_t)(s * 30 + 29 - t) * 2048; cb = 1024 + j;
                    if (t == 29) fdst = sentences + (size_t)s * 512 + 256 + j;
                } else if (grow < 1344) {
                    int b = grow - 1280;
                    xp = xw_head + (size_t)(b * 15 + t) * 2048; cb = j;
                    if (t == 14) fdst = headings + (size_t)b * 512 + j;
                } else {
                    int b = grow - 1344;
                    xp = xw_head + (size_t)(b * 15 + 14 - t) * 2048; cb = 1024 + j;
                    if (t == 14) fdst = headings + (size_t)b * 512 + 256 + j;
                }
                float gi = G[rr][uu * 4 + 0] + xp[cb];
                float gf = G[rr][uu * 4 + 1] + xp[cb + 256];
                float gg = G[rr][uu * 4 + 2] + xp[cb + 512];
                float go = G[rr][uu * 4 + 3] + xp[cb + 768];
                float cv = (t == 0) ? 0.f : cbuf[rr][uu];
                float cn = sigm(gf) * cv + sigm(gi) * tanhf(gg);
                float hn = sigm(go) * tanhf(cn);
                cbuf[rr][uu] = cn;
                hq[(size_t)grow * 256 + j] = f2bf(hn);
                if (fdst) *fdst = hn;
            }
        }
        grid.sync();
    }
}

// ============================================================================
// lstm_doc: persistent cooperative BiLSTM over 64 docs x 10 sentences.
// Rows: 0..63 fwd | 64..127 bwd.  Grid (2,16).  Writes every timestep into
// documents[b][s][512] (bwd half at +256, position-reversed).
// ============================================================================
__global__ __launch_bounds__(256, 2) void lstm_doc(
    const float* __restrict__ xw,
    const float* __restrict__ whh_f, const float* __restrict__ whh_b,
    unsigned short* hbA, unsigned short* hbB,
    float* __restrict__ documents)
{
    const int tid  = threadIdx.x;
    const int lane = tid & 63;
    const int w    = tid >> 6;
    const int n    = lane & 15;
    const int quad = lane >> 4;
    const int bx   = blockIdx.x;       // 0..1
    const int by   = blockIdx.y;       // 0..15
    const int r0   = bx * 64;
    const int u0   = by * 16;
    const bool bwd = (bx == 1);
    const float* whh = bwd ? whh_b : whh_f;

    __shared__ float G[64][65];
    __shared__ float cbuf[64][16];

    bf16x8 Bf[4][8];
#pragma unroll
    for (int ct = 0; ct < 4; ct++) {
        const int c    = ct * 16 + n;
        const int grow = (c & 3) * 256 + u0 + (c >> 2);
        const float* wr = whh + (size_t)grow * 256;
#pragma unroll
        for (int ks = 0; ks < 8; ks++) {
            union { bf16x8 v; short s[8]; } tmp;
            const float* p = wr + ks * 32 + quad * 8;
#pragma unroll
            for (int j = 0; j < 8; j++) tmp.s[j] = (short)f2bf(p[j]);
            Bf[ct][ks] = tmp.v;
        }
    }

    cg::grid_group grid = cg::this_grid();

    for (int t = 0; t < 10; t++) {
        const unsigned short* hp = (t & 1) ? hbB : hbA;
        unsigned short*       hq = (t & 1) ? hbA : hbB;
        {
            const unsigned short* hrow = hp + (size_t)(r0 + w * 16 + n) * 256;
            bf16x8 Af[8];
#pragma unroll
            for (int ks = 0; ks < 8; ks++)
                Af[ks] = *(const bf16x8*)(hrow + ks * 32 + quad * 8);
            f32x4 acc[4];
#pragma unroll
            for (int ct = 0; ct < 4; ct++) {
                acc[ct] = (f32x4){0.f, 0.f, 0.f, 0.f};
#pragma unroll
                for (int ks = 0; ks < 8; ks++)
                    acc[ct] = __builtin_amdgcn_mfma_f32_16x16x32_bf16(
                        Af[ks], Bf[ct][ks], acc[ct], 0, 0, 0);
            }
#pragma unroll
            for (int ct = 0; ct < 4; ct++)
#pragma unroll
                for (int r = 0; r < 4; r++)
                    G[w * 16 + quad * 4 + r][ct * 16 + n] = acc[ct][r];
        }
        __syncthreads();
        {
#pragma unroll
            for (int pp = 0; pp < 4; pp++) {
                const int idx = tid + pp * 256;
                const int rr = idx >> 4, uu = idx & 15;
                const int grow = r0 + rr;
                const int seq = grow & 63;
                const int j = u0 + uu;
                const float* xp;
                int cb, dpos, doff;
                if (!bwd) { xp = xw + (size_t)(seq * 10 + t) * 2048;     cb = j;        dpos = t;     doff = 0;   }
                else      { xp = xw + (size_t)(seq * 10 + 9 - t) * 2048; cb = 1024 + j; dpos = 9 - t; doff = 256; }
                float gi = G[rr][uu * 4 + 0] + xp[cb];
                float gf = G[rr][uu * 4 + 1] + xp[cb + 256];
                float gg = G[rr][uu * 4 + 2] + xp[cb + 512];
                float go = G[rr][uu * 4 + 3] + xp[cb + 768];
                float cv = (t == 0) ? 0.f : cbuf[rr][uu];
                float cn = sigm(gf) * cv + sigm(gi) * tanhf(gg);
                float hn = sigm(go) * tanhf(cn);
                cbuf[rr][uu] = cn;
                hq[(size_t)grow * 256 + j] = f2bf(hn);
                documents[(size_t)(seq * 10 + dpos) * 512 + doff + j] = hn;
            }
        }
        grid.sync();
    }
}

// SourceBias: biased[t] = tanh(sen[t] @ trans[u] + sb_bias[u]); block per token
__global__ __launch_bounds__(256) void source_bias(
    const float* __restrict__ sentences, const int* __restrict__ urls,
    const float* __restrict__ trans, const float* __restrict__ sb_bias,
    float* __restrict__ biased)
{
    const int tkn = blockIdx.x;
    const int u = urls[tkn];
    const float2* Tm = (const float2*)(trans + (size_t)u * 512 * 512);
    __shared__ float sv[512];
    for (int i = threadIdx.x; i < 512; i += 256) sv[i] = sentences[(size_t)tkn * 512 + i];
    __syncthreads();
    const int e = threadIdx.x;           // float2 column pair
    float ax = 0.f, ay = 0.f;
#pragma unroll 4
    for (int d = 0; d < 512; d++) {
        float s = sv[d];
        float2 tv = Tm[(size_t)d * 256 + e];
        ax += s * tv.x; ay += s * tv.y;
    }
    const float2 bv = ((const float2*)(sb_bias + (size_t)u * 512))[e];
    float2 o; o.x = tanhf(ax + bv.x); o.y = tanhf(ay + bv.y);
    ((float2*)biased)[(size_t)tkn * 256 + e] = o;
}

// v[b,d] = sum_e attn_W[d,e] * heading[b,e]; block per b
__global__ __launch_bounds__(256) void attn_v(
    const float* __restrict__ W, const float* __restrict__ headings,
    float* __restrict__ v)
{
    const int b = blockIdx.x;
    __shared__ float hh[512];
    for (int i = threadIdx.x; i < 512; i += 256) hh[i] = headings[(size_t)b * 512 + i];
    __syncthreads();
    for (int d = threadIdx.x; d < 512; d += 256) {
        float a = 0.f;
        const float* wr = W + (size_t)d * 512;
        for (int e = 0; e < 512; e++) a += wr[e] * hh[e];
        v[(size_t)b * 512 + d] = a;
    }
}

// scores -> softmax -> doc_rep -> both MLP heads; block per batch element
__global__ __launch_bounds__(256) void attn_heads(
    const float* __restrict__ documents, const float* __restrict__ v,
    const float* __restrict__ attn_b,
    const float* __restrict__ bW1, const float* __restrict__ bb1,
    const float* __restrict__ bW2, const float* __restrict__ bb2,
    const float* __restrict__ tW1, const float* __restrict__ tb1,
    const float* __restrict__ tW2, const float* __restrict__ tb2,
    float* __restrict__ out)
{
    const int b = blockIdx.x, tid = threadIdx.x;
    const int lane = tid & 63, wv_ = tid >> 6;
    __shared__ float vv[512], dr[512], h1s[256], t1s[256], sw[12], lg[5];
    for (int i = tid; i < 512; i += 256) vv[i] = v[(size_t)b * 512 + i];
    __syncthreads();
    for (int q = 0; q < 3; q++) {
        int s = q * 4 + wv_;
        float p = 0.f;
        if (s < 10) {
            const float* dp = documents + (size_t)(b * 10 + s) * 512;
            for (int d = lane; d < 512; d += 64) p += dp[d] * vv[d];
        }
#pragma unroll
        for (int off = 32; off > 0; off >>= 1) p += __shfl_down(p, off, 64);
        if (s < 10 && lane == 0) sw[s] = p + attn_b[0];
    }
    __syncthreads();
    if (tid == 0) {
        float mx = sw[0];
        for (int s = 1; s < 10; s++) mx = fmaxf(mx, sw[s]);
        float sum = 0.f;
        for (int s = 0; s < 10; s++) { sw[s] = expf(sw[s] - mx); sum += sw[s]; }
        for (int s = 0; s < 10; s++) sw[s] /= sum;
    }
    __syncthreads();
    for (int d = tid; d < 512; d += 256) {
        float a = 0.f;
#pragma unroll
        for (int s = 0; s < 10; s++) a += sw[s] * documents[(size_t)(b * 10 + s) * 512 + d];
        dr[d] = a;
    }
    __syncthreads();
    {
        float a = bb1[tid], a2 = tb1[tid];
        const float* w1 = bW1 + (size_t)tid * 512;
        const float* w2 = tW1 + (size_t)tid * 512;
        for (int k = 0; k < 512; k++) { float x = dr[k]; a += x * w1[k]; a2 += x * w2[k]; }
        h1s[tid] = tanhf(a); t1s[tid] = tanhf(a2);
    }
    __syncthreads();
    if (tid < 5) {
        float a = bb2[tid];
        const float* wp = bW2 + (size_t)tid * 256;
        for (int k = 0; k < 256; k++) a += h1s[k] * wp[k];
        lg[tid] = tanhf(a);
    }
    if (tid == 32) {
        float a = tb2[0];
        for (int k = 0; k < 256; k++) a += t1s[k] * tW2[k];
        out[320 + b] = 1.f / (1.f + expf(-tanhf(a)));
    }
    __syncthreads();
    if (tid == 0) {
        float mx = lg[0];
        for (int j = 1; j < 5; j++) mx = fmaxf(mx, lg[j]);
        float sum = 0.f, e[5];
        for (int j = 0; j < 5; j++) { e[j] = expf(lg[j] - mx); sum += e[j]; }
        for (int j = 0; j < 5; j++) out[b * 5 + j] = e[j] / sum;
    }
}

extern "C" void kernel_launch(void* const* d_in, const int* in_sizes, int n_in,
                              void* d_out, int out_size, void* d_ws, size_t ws_size,
                              hipStream_t stream)
{
    (void)in_sizes; (void)n_in; (void)out_size; (void)ws_size;
    const int*   input_ids = (const int*)d_in[0];
    const int*   urls      = (const int*)d_in[1];
    const int*   titles    = (const int*)d_in[2];
    const float* emb       = (const float*)d_in[3];
    const float* sen_wih_f = (const float*)d_in[4];
    const float* sen_whh_f = (const float*)d_in[5];
    const float* sen_b_f   = (const float*)d_in[6];
    const float* sen_wih_b = (const float*)d_in[7];
    const float* sen_whh_b = (const float*)d_in[8];
    const float* sen_b_b   = (const float*)d_in[9];
    const float* trans     = (const float*)d_in[10];
    const float* sb_bias   = (const float*)d_in[11];
    const float* doc_wih_f = (const float*)d_in[12];
    const float* doc_whh_f = (const float*)d_in[13];
    const float* doc_b_f   = (const float*)d_in[14];
    const float* doc_wih_b = (const float*)d_in[15];
    const float* doc_whh_b = (const float*)d_in[16];
    const float* doc_b_b   = (const float*)d_in[17];
    const float* attn_W    = (const float*)d_in[18];
    const float* attn_b    = (const float*)d_in[19];
    const float* bias_W1   = (const float*)d_in[20];
    const float* bias_b1   = (const float*)d_in[21];
    const float* bias_W2   = (const float*)d_in[22];
    const float* bias_b2   = (const float*)d_in[23];
    const float* truth_W1  = (const float*)d_in[24];
    const float* truth_b1  = (const float*)d_in[25];
    const float* truth_W2  = (const float*)d_in[26];
    const float* truth_b2  = (const float*)d_in[27];
    float* out = (float*)d_out;

    float* ws = (float*)d_ws;
    size_t off = 0;
    float* xw_all    = ws + off; off += (size_t)20160 * 2048;
    float* xw_doc    = ws + off; off += (size_t)640 * 2048;
    float* sentences = ws + off; off += (size_t)640 * 512;
    float* headings  = ws + off; off += (size_t)64 * 512;
    float* biased    = ws + off; off += (size_t)640 * 512;
    float* documents = ws + off; off += (size_t)64 * 10 * 512;
    float* vbuf      = ws + off; off += (size_t)64 * 512;
    unsigned short* hbA = (unsigned short*)(ws + off); off += (size_t)1408 * 128;
    unsigned short* hbB = (unsigned short*)(ws + off); off += (size_t)1408 * 128;
    unsigned short* hdA = (unsigned short*)(ws + off); off += (size_t)128 * 128;
    unsigned short* hdB = (unsigned short*)(ws + off); off += (size_t)128 * 128;
    float* xw_head = xw_all + (size_t)19200 * 2048;

    // zero initial hidden states (hbA..hbB and hdA..hdB are contiguous)
    hipMemsetAsync(hbA, 0, (size_t)2 * 1408 * 256 * 2, stream);
    hipMemsetAsync(hdA, 0, (size_t)2 * 128 * 256 * 2, stream);

    dim3 blk(256);

    // sentence+title input projection (gather + bf16 MFMA GEMM)
    proj_mfma<<<dim3(158, 32), blk, 0, stream>>>(
        emb, input_ids, titles, 19200, 20160, WEMB_K,
        sen_wih_f, sen_wih_b, sen_b_f, sen_b_b, xw_all);

    // persistent sentence/heading BiLSTM (30 steps, grid-synced)
    {
        void* args[] = { (void*)&xw_all, (void*)&xw_head,
                         (void*)&sen_whh_f, (void*)&sen_whh_b,
                         (void*)&hbA, (void*)&hbB,
                         (void*)&sentences, (void*)&headings };
        hipLaunchCooperativeKernel((const void*)lstm_sen, dim3(22, 16), blk,
                                   args, 0, stream);
    }

    source_bias<<<dim3(640), blk, 0, stream>>>(sentences, urls, trans, sb_bias, biased);

    // document input projection
    proj_mfma<<<dim3(5, 32), blk, 0, stream>>>(
        biased, nullptr, nullptr, 0, 640, 512,
        doc_wih_f, doc_wih_b, doc_b_f, doc_b_b, xw_doc);

    // persistent document BiLSTM (10 steps)
    {
        void* args[] = { (void*)&xw_doc,
                         (void*)&doc_whh_f, (void*)&doc_whh_b,
                         (void*)&hdA, (void*)&hdB,
                         (void*)&documents };
        hipLaunchCooperativeKernel((const void*)lstm_doc, dim3(2, 16), blk,
                                   args, 0, stream);
    }

    attn_v<<<dim3(64), blk, 0, stream>>>(attn_W, headings, vbuf);
    attn_heads<<<dim3(64), blk, 0, stream>>>(documents, vbuf, attn_b,
                                             bias_W1, bias_b1, bias_W2, bias_b2,
                                             truth_W1, truth_b1, truth_W2, truth_b2,
                                             out);
}

// Round 4
// 1591.065 us; speedup vs baseline: 1.6235x; 1.6235x over previous
//
#include <hip/hip_runtime.h>
#include <cstddef>

typedef short bf16x8 __attribute__((ext_vector_type(8)));
typedef float f32x4 __attribute__((ext_vector_type(4)));

__device__ __forceinline__ float sigm(float x) { return 1.f / (1.f + expf(-x)); }

// f32 -> bf16 (round to nearest even)
__device__ __forceinline__ unsigned short f2bf(float f) {
    union { float f; unsigned u; } v; v.f = f;
    return (unsigned short)((v.u + 0x7FFFu + ((v.u >> 16) & 1u)) >> 16);
}

// ============================================================================
// prep_cast: one pass producing all bf16 operands.
//  region0: Abf[20160][320bf16]  = emb rows gathered by input_ids(19200)+titles(960)
//  region1: Wsen[2048][320bf16]  = [sen_wih_f | sen_wih_b] (K 300 -> 320 zero-pad)
//  region2: Wdoc[2048][512bf16]  = [doc_wih_f | doc_wih_b]
// One uint (2 bf16) per thread.  Sizes in UINTS: row = Kbf16/2.
// ============================================================================
#define N0 (20160 * 160)
#define N1 (2048 * 160)
#define N2 (2048 * 256)

__global__ __launch_bounds__(256) void prep_cast(
    const int* __restrict__ ids, const int* __restrict__ titles,
    const float* __restrict__ emb,
    const float* __restrict__ swf, const float* __restrict__ swb,
    const float* __restrict__ dwf, const float* __restrict__ dwb,
    unsigned* __restrict__ Abf, unsigned* __restrict__ Wsen,
    unsigned* __restrict__ Wdoc)
{
    int idx = blockIdx.x * 256 + threadIdx.x;
    if (idx < N0) {
        int row = idx / 160, kk = idx - row * 160;
        int id = (row < 19200) ? ids[row] : titles[row - 19200];
        float a = 0.f, b = 0.f;
        if (kk < 150) {
            const float* s = emb + (size_t)id * 300 + kk * 2;
            a = s[0]; b = s[1];
        }
        Abf[idx] = (unsigned)f2bf(a) | ((unsigned)f2bf(b) << 16);
    } else if (idx < N0 + N1) {
        int j = idx - N0;
        int row = j / 160, kk = j - row * 160;
        const float* base = (row < 1024) ? swf + (size_t)row * 300
                                         : swb + (size_t)(row - 1024) * 300;
        float a = 0.f, b = 0.f;
        if (kk < 150) { a = base[kk * 2]; b = base[kk * 2 + 1]; }
        Wsen[j] = (unsigned)f2bf(a) | ((unsigned)f2bf(b) << 16);
    } else if (idx < N0 + N1 + N2) {
        int j = idx - N0 - N1;
        int row = j >> 8, kk = j & 255;
        const float* base = (row < 1024) ? dwf + (size_t)row * 512
                                         : dwb + (size_t)(row - 1024) * 512;
        Wdoc[j] = (unsigned)f2bf(base[kk * 2]) | ((unsigned)f2bf(base[kk * 2 + 1]) << 16);
    }
}

// ============================================================================
// proj_mfma: out[M][2048] = Abf[M][Kp] @ Wbf^T + bias, output GATE-INTERLEAVED:
//   col = half*1024 + unit*4 + gate   (unit 0..255, gate 0..3 = i,f,g,o)
// Wbf rows in original order [half*1024 + gate*256 + unit]; LDS gather applies
// the permutation. BM=128, BN=128 (32 units x 4 gates), BK=32 bf16.
// ============================================================================
__global__ __launch_bounds__(256) void proj_mfma(
    const unsigned short* __restrict__ Abf, int M, int Kp,
    const unsigned short* __restrict__ Wbf,
    const float* __restrict__ bf_, const float* __restrict__ bb_,
    float* __restrict__ out)
{
    __shared__ unsigned short As[128 * 40];   // pitch 80B (16B aligned)
    __shared__ unsigned short Ws[128 * 40];
    const int tid  = threadIdx.x;
    const int lane = tid & 63;
    const int w    = tid >> 6;
    const int n    = lane & 15;
    const int quad = lane >> 4;
    const int bm   = blockIdx.x * 128;
    const int by   = blockIdx.y;              // 0..15
    const int half = by >> 3;
    const int ug32 = (by & 7) * 32;
    const unsigned short* Wb = Wbf + (size_t)half * 1024 * Kp;
    const float* biasp = half ? bb_ : bf_;

    f32x4 acc[2][8];
#pragma unroll
    for (int rt = 0; rt < 2; rt++)
#pragma unroll
        for (int ct = 0; ct < 8; ct++) acc[rt][ct] = (f32x4){0.f, 0.f, 0.f, 0.f};

    const int chunks = Kp >> 5;
    for (int kc = 0; kc < chunks; kc++) {
        const int k0 = kc * 32;
#pragma unroll
        for (int j = 0; j < 2; j++) {
            int idx = j * 256 + tid;
            int arow = idx >> 2, qq = idx & 3;
            int grow = bm + arow; if (grow >= M) grow = M - 1;
            *(uint4*)&As[arow * 40 + qq * 8] =
                *(const uint4*)(Abf + (size_t)grow * Kp + k0 + qq * 8);
            int cc = idx >> 2;
            int wrow = (cc >> 5) * 256 + ug32 + (cc & 31);   // gate=cc>>5, unit
            *(uint4*)&Ws[cc * 40 + qq * 8] =
                *(const uint4*)(Wb + (size_t)wrow * Kp + k0 + qq * 8);
        }
        __syncthreads();
        bf16x8 Aq[2], Bq[8];
#pragma unroll
        for (int rt = 0; rt < 2; rt++)
            Aq[rt] = *(const bf16x8*)&As[((w * 2 + rt) * 16 + n) * 40 + quad * 8];
#pragma unroll
        for (int ct = 0; ct < 8; ct++)
            Bq[ct] = *(const bf16x8*)&Ws[(ct * 16 + n) * 40 + quad * 8];
#pragma unroll
        for (int rt = 0; rt < 2; rt++)
#pragma unroll
            for (int ct = 0; ct < 8; ct++)
                acc[rt][ct] = __builtin_amdgcn_mfma_f32_16x16x32_bf16(
                    Aq[rt], Bq[ct], acc[rt][ct], 0, 0, 0);
        __syncthreads();
    }

    // acc[ct] covers MFMA cols cc=ct*16+n: gate=ct>>1, unit uL=(ct&1)*16+n
#pragma unroll
    for (int s = 0; s < 2; s++) {
        const int uL = s * 16 + n;
        float b0 = biasp[ug32 + uL];
        float b1 = biasp[256 + ug32 + uL];
        float b2 = biasp[512 + ug32 + uL];
        float b3 = biasp[768 + ug32 + uL];
#pragma unroll
        for (int rt = 0; rt < 2; rt++) {
#pragma unroll
            for (int r = 0; r < 4; r++) {
                int row = bm + (w * 2 + rt) * 16 + quad * 4 + r;
                if (row >= M) continue;
                float4 o;
                o.x = acc[rt][0 + s][r] + b0;
                o.y = acc[rt][2 + s][r] + b1;
                o.z = acc[rt][4 + s][r] + b2;
                o.w = acc[rt][6 + s][r] + b3;
                *(float4*)(out + (size_t)row * 2048 + half * 1024 + (ug32 + uL) * 4) = o;
            }
        }
    }
}

// ---------------------------------------------------------------------------
// group barrier: 16 blocks sharing one row-group, agent-scope atomics.
// ---------------------------------------------------------------------------
__device__ __forceinline__ void group_barrier(unsigned* bcnt, unsigned* bgen) {
    __syncthreads();
    if (threadIdx.x == 0) {
        unsigned g = __hip_atomic_load(bgen, __ATOMIC_RELAXED, __HIP_MEMORY_SCOPE_AGENT);
        unsigned old = __hip_atomic_fetch_add(bcnt, 1u, __ATOMIC_RELEASE, __HIP_MEMORY_SCOPE_AGENT);
        if (old == 15u) {
            __hip_atomic_store(bcnt, 0u, __ATOMIC_RELAXED, __HIP_MEMORY_SCOPE_AGENT);
            __hip_atomic_store(bgen, g + 1u, __ATOMIC_RELEASE, __HIP_MEMORY_SCOPE_AGENT);
        } else {
            while (__hip_atomic_load(bgen, __ATOMIC_ACQUIRE, __HIP_MEMORY_SCOPE_AGENT) == g)
                __builtin_amdgcn_s_sleep(1);
        }
    }
    __syncthreads();
}

// ============================================================================
// lstm_sen: persistent BiLSTM, grid (16 unit-groups, 22 row-groups).
// Rows: 0..639 sen-fwd | 640..1279 sen-bwd | 1280..1343 head-f | 1344..1407 head-b.
// ============================================================================
__global__ __launch_bounds__(256, 2) void lstm_sen(
    const float* __restrict__ xw, const float* __restrict__ xw_head,
    const float* __restrict__ whh_f, const float* __restrict__ whh_b,
    unsigned short* hbA, unsigned short* hbB,
    float* __restrict__ sentences, float* __restrict__ headings,
    unsigned* bars)
{
    const int tid  = threadIdx.x;
    const int lane = tid & 63;
    const int w    = tid >> 6;
    const int n    = lane & 15;
    const int quad = lane >> 4;
    const int ug   = blockIdx.x;       // 0..15
    const int rg   = blockIdx.y;       // 0..21
    const int r0   = rg * 64;
    const int u0   = ug * 16;
    const bool bwd  = (rg >= 10 && rg < 20) || (rg == 21);
    const bool head = (rg >= 20);
    const float* whh = bwd ? whh_b : whh_f;
    unsigned* bcnt = bars + rg * 2;
    unsigned* bgen = bars + rg * 2 + 1;

    __shared__ float G[64][68];        // row pitch 272B (16B aligned)

    // Whh -> register B-frags. MFMA col cc=ct*16+n -> (unit uL=cc>>2, gate=cc&3);
    // W row = gate*256 + u0 + uL.
    bf16x8 Bf[4][8];
#pragma unroll
    for (int ct = 0; ct < 4; ct++) {
        const int c    = ct * 16 + n;
        const int grow = (c & 3) * 256 + u0 + (c >> 2);
        const float* wr = whh + (size_t)grow * 256;
#pragma unroll
        for (int ks = 0; ks < 8; ks++) {
            union { bf16x8 v; short s[8]; } tmp;
            const float* p = wr + ks * 32 + quad * 8;
#pragma unroll
            for (int j = 0; j < 8; j++) tmp.s[j] = (short)f2bf(p[j]);
            Bf[ct][ks] = tmp.v;
        }
    }

    float cr[4] = {0.f, 0.f, 0.f, 0.f};
    const int rr = tid >> 2;
    const int us = (tid & 3) * 4;             // local unit base
    const int grow_e = r0 + rr;

    for (int t = 0; t < 30; t++) {
        const unsigned short* hp = (t & 1) ? hbB : hbA;
        unsigned short*       hq = (t & 1) ? hbA : hbB;
        const bool active = !(head && t >= 15);
        float4 xv[4];
        float* fdst = nullptr;
        if (active) {
            const float* xbase;
            if (grow_e < 640) {
                xbase = xw + ((size_t)grow_e * 30 + t) * 2048;
                if (t == 29) fdst = sentences + (size_t)grow_e * 512;
            } else if (grow_e < 1280) {
                int s = grow_e - 640;
                xbase = xw + ((size_t)s * 30 + 29 - t) * 2048 + 1024;
                if (t == 29) fdst = sentences + (size_t)s * 512 + 256;
            } else if (grow_e < 1344) {
                int b = grow_e - 1280;
                xbase = xw_head + ((size_t)b * 15 + t) * 2048;
                if (t == 14) fdst = headings + (size_t)b * 512;
            } else {
                int b = grow_e - 1344;
                xbase = xw_head + ((size_t)b * 15 + 14 - t) * 2048 + 1024;
                if (t == 14) fdst = headings + (size_t)b * 512 + 256;
            }
            const float4* xp = (const float4*)(xbase + (size_t)(u0 + us) * 4);
            xv[0] = xp[0]; xv[1] = xp[1]; xv[2] = xp[2]; xv[3] = xp[3];

            const unsigned long long* hrow =
                (const unsigned long long*)(hp + (size_t)(r0 + w * 16 + n) * 256);
            unsigned long long a0[8], a1[8];
#pragma unroll
            for (int ks = 0; ks < 8; ks++) {
                a0[ks] = __hip_atomic_load(hrow + ks * 8 + quad * 2,
                                           __ATOMIC_RELAXED, __HIP_MEMORY_SCOPE_AGENT);
                a1[ks] = __hip_atomic_load(hrow + ks * 8 + quad * 2 + 1,
                                           __ATOMIC_RELAXED, __HIP_MEMORY_SCOPE_AGENT);
            }
            f32x4 acc[4];
#pragma unroll
            for (int ct = 0; ct < 4; ct++) acc[ct] = (f32x4){0.f, 0.f, 0.f, 0.f};
#pragma unroll
            for (int ks = 0; ks < 8; ks++) {
                union { bf16x8 v; unsigned long long q[2]; } af;
                af.q[0] = a0[ks]; af.q[1] = a1[ks];
#pragma unroll
                for (int ct = 0; ct < 4; ct++)
                    acc[ct] = __builtin_amdgcn_mfma_f32_16x16x32_bf16(
                        af.v, Bf[ct][ks], acc[ct], 0, 0, 0);
            }
#pragma unroll
            for (int ct = 0; ct < 4; ct++)
#pragma unroll
                for (int r = 0; r < 4; r++)
                    G[w * 16 + quad * 4 + r][ct * 16 + n] = acc[ct][r];
        }
        __syncthreads();
        if (active) {
            const float4* Gp = (const float4*)&G[rr][us * 4];
            unsigned long long hpack = 0ull;
            float hout[4];
#pragma unroll
            for (int p = 0; p < 4; p++) {
                float4 gv = Gp[p];
                float4 xq = xv[p];
                float gi = gv.x + xq.x;
                float gf = gv.y + xq.y;
                float gg = gv.z + xq.z;
                float go = gv.w + xq.w;
                float cn = sigm(gf) * cr[p] + sigm(gi) * tanhf(gg);
                float hn = sigm(go) * tanhf(cn);
                cr[p] = cn; hout[p] = hn;
                hpack |= ((unsigned long long)f2bf(hn)) << (16 * p);
            }
            __hip_atomic_store((unsigned long long*)(hq + (size_t)grow_e * 256 + u0 + us),
                               hpack, __ATOMIC_RELAXED, __HIP_MEMORY_SCOPE_AGENT);
            if (fdst) *(float4*)(fdst + u0 + us) = *(float4*)hout;
        }
        if (t < 29) group_barrier(bcnt, bgen);
    }
}

// ============================================================================
// lstm_doc: persistent BiLSTM over 64 docs x 10 steps. Grid (16, 2).
// ============================================================================
__global__ __launch_bounds__(256, 2) void lstm_doc(
    const float* __restrict__ xw,
    const float* __restrict__ whh_f, const float* __restrict__ whh_b,
    unsigned short* hbA, unsigned short* hbB,
    float* __restrict__ documents,
    unsigned* bars)
{
    const int tid  = threadIdx.x;
    const int lane = tid & 63;
    const int w    = tid >> 6;
    const int n    = lane & 15;
    const int quad = lane >> 4;
    const int ug   = blockIdx.x;       // 0..15
    const int rg   = blockIdx.y;       // 0..1
    const int r0   = rg * 64;
    const int u0   = ug * 16;
    const bool bwd = (rg == 1);
    const float* whh = bwd ? whh_b : whh_f;
    unsigned* bcnt = bars + rg * 2;
    unsigned* bgen = bars + rg * 2 + 1;

    __shared__ float G[64][68];

    bf16x8 Bf[4][8];
#pragma unroll
    for (int ct = 0; ct < 4; ct++) {
        const int c    = ct * 16 + n;
        const int grow = (c & 3) * 256 + u0 + (c >> 2);
        const float* wr = whh + (size_t)grow * 256;
#pragma unroll
        for (int ks = 0; ks < 8; ks++) {
            union { bf16x8 v; short s[8]; } tmp;
            const float* p = wr + ks * 32 + quad * 8;
#pragma unroll
            for (int j = 0; j < 8; j++) tmp.s[j] = (short)f2bf(p[j]);
            Bf[ct][ks] = tmp.v;
        }
    }

    float cr[4] = {0.f, 0.f, 0.f, 0.f};
    const int rr = tid >> 2;
    const int us = (tid & 3) * 4;
    const int grow_e = r0 + rr;
    const int seq = rr;                        // doc index

    for (int t = 0; t < 10; t++) {
        const unsigned short* hp = (t & 1) ? hbB : hbA;
        unsigned short*       hq = (t & 1) ? hbA : hbB;
        const float* xbase;
        int dpos, doff;
        if (!bwd) { xbase = xw + ((size_t)seq * 10 + t) * 2048;            dpos = t;     doff = 0;   }
        else      { xbase = xw + ((size_t)seq * 10 + 9 - t) * 2048 + 1024; dpos = 9 - t; doff = 256; }
        const float4* xp = (const float4*)(xbase + (size_t)(u0 + us) * 4);
        float4 xv0 = xp[0], xv1 = xp[1], xv2 = xp[2], xv3 = xp[3];

        const unsigned long long* hrow =
            (const unsigned long long*)(hp + (size_t)(r0 + w * 16 + n) * 256);
        unsigned long long a0[8], a1[8];
#pragma unroll
        for (int ks = 0; ks < 8; ks++) {
            a0[ks] = __hip_atomic_load(hrow + ks * 8 + quad * 2,
                                       __ATOMIC_RELAXED, __HIP_MEMORY_SCOPE_AGENT);
            a1[ks] = __hip_atomic_load(hrow + ks * 8 + quad * 2 + 1,
                                       __ATOMIC_RELAXED, __HIP_MEMORY_SCOPE_AGENT);
        }
        f32x4 acc[4];
#pragma unroll
        for (int ct = 0; ct < 4; ct++) acc[ct] = (f32x4){0.f, 0.f, 0.f, 0.f};
#pragma unroll
        for (int ks = 0; ks < 8; ks++) {
            union { bf16x8 v; unsigned long long q[2]; } af;
            af.q[0] = a0[ks]; af.q[1] = a1[ks];
#pragma unroll
            for (int ct = 0; ct < 4; ct++)
                acc[ct] = __builtin_amdgcn_mfma_f32_16x16x32_bf16(
                    af.v, Bf[ct][ks], acc[ct], 0, 0, 0);
        }
#pragma unroll
        for (int ct = 0; ct < 4; ct++)
#pragma unroll
            for (int r = 0; r < 4; r++)
                G[w * 16 + quad * 4 + r][ct * 16 + n] = acc[ct][r];
        __syncthreads();
        {
            const float4* Gp = (const float4*)&G[rr][us * 4];
            float4 xvv[4] = {xv0, xv1, xv2, xv3};
            unsigned long long hpack = 0ull;
            float hout[4];
#pragma unroll
            for (int p = 0; p < 4; p++) {
                float4 gv = Gp[p];
                float gi = gv.x + xvv[p].x;
                float gf = gv.y + xvv[p].y;
                float gg = gv.z + xvv[p].z;
                float go = gv.w + xvv[p].w;
                float cn = sigm(gf) * cr[p] + sigm(gi) * tanhf(gg);
                float hn = sigm(go) * tanhf(cn);
                cr[p] = cn; hout[p] = hn;
                hpack |= ((unsigned long long)f2bf(hn)) << (16 * p);
            }
            __hip_atomic_store((unsigned long long*)(hq + (size_t)grow_e * 256 + u0 + us),
                               hpack, __ATOMIC_RELAXED, __HIP_MEMORY_SCOPE_AGENT);
            *(float4*)(documents + (size_t)(seq * 10 + dpos) * 512 + doff + u0 + us) =
                *(float4*)hout;
        }
        if (t < 9) group_barrier(bcnt, bgen);
    }
}

// SourceBias: biasedBf[t] = bf16(tanh(sen[t] @ trans[u] + sb_bias[u]))
__global__ __launch_bounds__(256) void source_bias(
    const float* __restrict__ sentences, const int* __restrict__ urls,
    const float* __restrict__ trans, const float* __restrict__ sb_bias,
    unsigned* __restrict__ biasedBf)
{
    const int tkn = blockIdx.x;
    const int u = urls[tkn];
    const float2* Tm = (const float2*)(trans + (size_t)u * 512 * 512);
    __shared__ float sv[512];
    for (int i = threadIdx.x; i < 512; i += 256) sv[i] = sentences[(size_t)tkn * 512 + i];
    __syncthreads();
    const int e = threadIdx.x;               // column pair (2e, 2e+1)
    float ax = 0.f, ay = 0.f;
#pragma unroll 4
    for (int d = 0; d < 512; d++) {
        float s = sv[d];
        float2 tv = Tm[(size_t)d * 256 + e];
        ax += s * tv.x; ay += s * tv.y;
    }
    const float2 bv = ((const float2*)(sb_bias + (size_t)u * 512))[e];
    float x = tanhf(ax + bv.x), y = tanhf(ay + bv.y);
    biasedBf[(size_t)tkn * 256 + e] = (unsigned)f2bf(x) | ((unsigned)f2bf(y) << 16);
}

// v[b,d] = sum_e attn_W[d,e] * heading[b,e]; block per b
__global__ __launch_bounds__(256) void attn_v(
    const float* __restrict__ W, const float* __restrict__ headings,
    float* __restrict__ v)
{
    const int b = blockIdx.x;
    __shared__ float hh[512];
    for (int i = threadIdx.x; i < 512; i += 256) hh[i] = headings[(size_t)b * 512 + i];
    __syncthreads();
    for (int d = threadIdx.x; d < 512; d += 256) {
        float a = 0.f;
        const float* wr = W + (size_t)d * 512;
        for (int e = 0; e < 512; e++) a += wr[e] * hh[e];
        v[(size_t)b * 512 + d] = a;
    }
}

// scores -> softmax -> doc_rep -> both MLP heads; block per batch element
__global__ __launch_bounds__(256) void attn_heads(
    const float* __restrict__ documents, const float* __restrict__ v,
    const float* __restrict__ attn_b,
    const float* __restrict__ bW1, const float* __restrict__ bb1,
    const float* __restrict__ bW2, const float* __restrict__ bb2,
    const float* __restrict__ tW1, const float* __restrict__ tb1,
    const float* __restrict__ tW2, const float* __restrict__ tb2,
    float* __restrict__ out)
{
    const int b = blockIdx.x, tid = threadIdx.x;
    const int lane = tid & 63, wv_ = tid >> 6;
    __shared__ float vv[512], dr[512], h1s[256], t1s[256], sw[12], lg[5];
    for (int i = tid; i < 512; i += 256) vv[i] = v[(size_t)b * 512 + i];
    __syncthreads();
    for (int q = 0; q < 3; q++) {
        int s = q * 4 + wv_;
        float p = 0.f;
        if (s < 10) {
            const float* dp = documents + (size_t)(b * 10 + s) * 512;
            for (int d = lane; d < 512; d += 64) p += dp[d] * vv[d];
        }
#pragma unroll
        for (int off = 32; off > 0; off >>= 1) p += __shfl_down(p, off, 64);
        if (s < 10 && lane == 0) sw[s] = p + attn_b[0];
    }
    __syncthreads();
    if (tid == 0) {
        float mx = sw[0];
        for (int s = 1; s < 10; s++) mx = fmaxf(mx, sw[s]);
        float sum = 0.f;
        for (int s = 0; s < 10; s++) { sw[s] = expf(sw[s] - mx); sum += sw[s]; }
        for (int s = 0; s < 10; s++) sw[s] /= sum;
    }
    __syncthreads();
    for (int d = tid; d < 512; d += 256) {
        float a = 0.f;
#pragma unroll
        for (int s = 0; s < 10; s++) a += sw[s] * documents[(size_t)(b * 10 + s) * 512 + d];
        dr[d] = a;
    }
    __syncthreads();
    {
        float a = bb1[tid], a2 = tb1[tid];
        const float* w1 = bW1 + (size_t)tid * 512;
        const float* w2 = tW1 + (size_t)tid * 512;
        for (int k = 0; k < 512; k++) { float x = dr[k]; a += x * w1[k]; a2 += x * w2[k]; }
        h1s[tid] = tanhf(a); t1s[tid] = tanhf(a2);
    }
    __syncthreads();
    if (tid < 5) {
        float a = bb2[tid];
        const float* wp = bW2 + (size_t)tid * 256;
        for (int k = 0; k < 256; k++) a += h1s[k] * wp[k];
        lg[tid] = tanhf(a);
    }
    if (tid == 32) {
        float a = tb2[0];
        for (int k = 0; k < 256; k++) a += t1s[k] * tW2[k];
        out[320 + b] = 1.f / (1.f + expf(-tanhf(a)));
    }
    __syncthreads();
    if (tid == 0) {
        float mx = lg[0];
        for (int j = 1; j < 5; j++) mx = fmaxf(mx, lg[j]);
        float sum = 0.f, e[5];
        for (int j = 0; j < 5; j++) { e[j] = expf(lg[j] - mx); sum += e[j]; }
        for (int j = 0; j < 5; j++) out[b * 5 + j] = e[j] / sum;
    }
}

extern "C" void kernel_launch(void* const* d_in, const int* in_sizes, int n_in,
                              void* d_out, int out_size, void* d_ws, size_t ws_size,
                              hipStream_t stream)
{
    (void)in_sizes; (void)n_in; (void)out_size; (void)ws_size;
    const int*   input_ids = (const int*)d_in[0];
    const int*   urls      = (const int*)d_in[1];
    const int*   titles    = (const int*)d_in[2];
    const float* emb       = (const float*)d_in[3];
    const float* sen_wih_f = (const float*)d_in[4];
    const float* sen_whh_f = (const float*)d_in[5];
    const float* sen_b_f   = (const float*)d_in[6];
    const float* sen_wih_b = (const float*)d_in[7];
    const float* sen_whh_b = (const float*)d_in[8];
    const float* sen_b_b   = (const float*)d_in[9];
    const float* trans     = (const float*)d_in[10];
    const float* sb_bias   = (const float*)d_in[11];
    const float* doc_wih_f = (const float*)d_in[12];
    const float* doc_whh_f = (const float*)d_in[13];
    const float* doc_b_f   = (const float*)d_in[14];
    const float* doc_wih_b = (const float*)d_in[15];
    const float* doc_whh_b = (const float*)d_in[16];
    const float* doc_b_b   = (const float*)d_in[17];
    const float* attn_W    = (const float*)d_in[18];
    const float* attn_b    = (const float*)d_in[19];
    const float* bias_W1   = (const float*)d_in[20];
    const float* bias_b1   = (const float*)d_in[21];
    const float* bias_W2   = (const float*)d_in[22];
    const float* bias_b2   = (const float*)d_in[23];
    const float* truth_W1  = (const float*)d_in[24];
    const float* truth_b1  = (const float*)d_in[25];
    const float* truth_W2  = (const float*)d_in[26];
    const float* truth_b2  = (const float*)d_in[27];
    float* out = (float*)d_out;

    // ------------------------------------------------------------------
    // Workspace layout with lifetime overlays (all offsets in FLOATS).
    // Slot A = xw_all [0 .. 41,287,680): live D2(proj#1 write)–D3(lstm_sen read).
    //   After D3, overlaid by: biasedBf(+0, 163,840), xw_doc(+163,840,
    //   1,310,720), documents(+1,474,560, 327,680), vbuf(+1,802,240, 32,768).
    // Slot B = Abf [41,287,680 .. +3,225,600): live D1–D2 (proj#1 read).
    //   After D2, overlaid by: sentences(+0), headings(+327,680),
    //   hbA(+360,448), hbB(+540,672), hdA(+720,896), hdB(+737,280),
    //   bars(+753,664). Memsets for hbA/hdA/bars run AFTER proj#1.
    // Slot C = Wsen [44,513,280 .. +327,680): D1–D2.
    // Slot D = Wdoc [44,840,960 .. +524,288): D1–D5.
    // Total 45,365,248 floats = 181.5 MB (< R2's proven 183.3 MB).
    // ------------------------------------------------------------------
    float* ws = (float*)d_ws;
    float* xw_all      = ws;
    float* xw_head     = xw_all + (size_t)19200 * 2048;
    unsigned* biasedBf = (unsigned*)(ws + 0);
    float* xw_doc      = ws + 163840;
    float* documents   = ws + 1474560;
    float* vbuf        = ws + 1802240;

    float* slotB       = ws + 41287680;
    unsigned* Abf      = (unsigned*)slotB;
    float* sentences   = slotB;
    float* headings    = slotB + 327680;
    unsigned short* hbA = (unsigned short*)(slotB + 360448);
    unsigned short* hbB = (unsigned short*)(slotB + 540672);
    unsigned short* hdA = (unsigned short*)(slotB + 720896);
    unsigned short* hdB = (unsigned short*)(slotB + 737280);
    unsigned* barsS    = (unsigned*)(slotB + 753664);   // 44 uints used
    unsigned* barsD    = barsS + 48;                    // 4 uints used

    unsigned* Wsen     = (unsigned*)(ws + 44513280);
    unsigned* Wdoc     = (unsigned*)(ws + 44840960);

    dim3 blk(256);

    // D1: gather + bf16 casts
    prep_cast<<<dim3((N0 + N1 + N2 + 255) / 256), blk, 0, stream>>>(
        input_ids, titles, emb, sen_wih_f, sen_wih_b, doc_wih_f, doc_wih_b,
        Abf, Wsen, Wdoc);

    // D2: sentence+title input projection (reads Abf/Wsen, writes xw_all)
    proj_mfma<<<dim3(158, 16), blk, 0, stream>>>(
        (const unsigned short*)Abf, 20160, 320,
        (const unsigned short*)Wsen, sen_b_f, sen_b_b, xw_all);

    // Zero-init h states + barriers (slot B is dead now; Abf fully consumed)
    hipMemsetAsync(hbA, 0, (size_t)1408 * 256 * 2, stream);
    hipMemsetAsync(hdA, 0, (size_t)128 * 256 * 2, stream);
    hipMemsetAsync(barsS, 0, 64 * sizeof(unsigned), stream);

    // D3: persistent sentence/heading BiLSTM
    lstm_sen<<<dim3(16, 22), blk, 0, stream>>>(
        xw_all, xw_head, sen_whh_f, sen_whh_b, hbA, hbB,
        sentences, headings, barsS);

    // D4: SourceBias (reads sentences, writes biasedBf into dead xw_all slot)
    source_bias<<<dim3(640), blk, 0, stream>>>(sentences, urls, trans, sb_bias, biasedBf);

    // D5: document input projection
    proj_mfma<<<dim3(5, 16), blk, 0, stream>>>(
        (const unsigned short*)biasedBf, 640, 512,
        (const unsigned short*)Wdoc, doc_b_f, doc_b_b, xw_doc);

    // D6: persistent document BiLSTM
    lstm_doc<<<dim3(16, 2), blk, 0, stream>>>(
        xw_doc, doc_whh_f, doc_whh_b, hdA, hdB, documents, barsD);

    // D7/D8: attention + heads
    attn_v<<<dim3(64), blk, 0, stream>>>(attn_W, headings, vbuf);
    attn_heads<<<dim3(64), blk, 0, stream>>>(documents, vbuf, attn_b,
                                             bias_W1, bias_b1, bias_W2, bias_b2,
                                             truth_W1, truth_b1, truth_W2, truth_b2,
                                             out);
}

// Round 5
// 748.136 us; speedup vs baseline: 3.4528x; 2.1267x over previous
//
#include <hip/hip_runtime.h>
#include <cstddef>

typedef short bf16x8 __attribute__((ext_vector_type(8)));
typedef float f32x4 __attribute__((ext_vector_type(4)));

__device__ __forceinline__ float sigm(float x) { return 1.f / (1.f + expf(-x)); }

// f32 -> bf16 (round to nearest even)
__device__ __forceinline__ unsigned short f2bf(float f) {
    union { float f; unsigned u; } v; v.f = f;
    return (unsigned short)((v.u + 0x7FFFu + ((v.u >> 16) & 1u)) >> 16);
}

// ============================================================================
// prep_cast: one pass producing all bf16 operands.
//  region0: Abf[20160][320bf16]  = emb rows gathered by input_ids(19200)+titles(960)
//  region1: Wsen[2048][320bf16]  = [sen_wih_f | sen_wih_b] (K 300 -> 320 zero-pad)
//  region2: Wdoc[2048][512bf16]  = [doc_wih_f | doc_wih_b]
// ============================================================================
#define N0 (20160 * 160)
#define N1 (2048 * 160)
#define N2 (2048 * 256)

__global__ __launch_bounds__(256) void prep_cast(
    const int* __restrict__ ids, const int* __restrict__ titles,
    const float* __restrict__ emb,
    const float* __restrict__ swf, const float* __restrict__ swb,
    const float* __restrict__ dwf, const float* __restrict__ dwb,
    unsigned* __restrict__ Abf, unsigned* __restrict__ Wsen,
    unsigned* __restrict__ Wdoc)
{
    int idx = blockIdx.x * 256 + threadIdx.x;
    if (idx < N0) {
        int row = idx / 160, kk = idx - row * 160;
        int id = (row < 19200) ? ids[row] : titles[row - 19200];
        float a = 0.f, b = 0.f;
        if (kk < 150) {
            const float* s = emb + (size_t)id * 300 + kk * 2;
            a = s[0]; b = s[1];
        }
        Abf[idx] = (unsigned)f2bf(a) | ((unsigned)f2bf(b) << 16);
    } else if (idx < N0 + N1) {
        int j = idx - N0;
        int row = j / 160, kk = j - row * 160;
        const float* base = (row < 1024) ? swf + (size_t)row * 300
                                         : swb + (size_t)(row - 1024) * 300;
        float a = 0.f, b = 0.f;
        if (kk < 150) { a = base[kk * 2]; b = base[kk * 2 + 1]; }
        Wsen[j] = (unsigned)f2bf(a) | ((unsigned)f2bf(b) << 16);
    } else if (idx < N0 + N1 + N2) {
        int j = idx - N0 - N1;
        int row = j >> 8, kk = j & 255;
        const float* base = (row < 1024) ? dwf + (size_t)row * 512
                                         : dwb + (size_t)(row - 1024) * 512;
        Wdoc[j] = (unsigned)f2bf(base[kk * 2]) | ((unsigned)f2bf(base[kk * 2 + 1]) << 16);
    }
}

// ============================================================================
// proj_mfma: out[M][2048] = Abf[M][Kp] @ Wbf^T + bias, output GATE-INTERLEAVED:
//   col = half*1024 + unit*4 + gate   (unit 0..255, gate 0..3 = i,f,g,o)
// ============================================================================
__global__ __launch_bounds__(256) void proj_mfma(
    const unsigned short* __restrict__ Abf, int M, int Kp,
    const unsigned short* __restrict__ Wbf,
    const float* __restrict__ bf_, const float* __restrict__ bb_,
    float* __restrict__ out)
{
    __shared__ unsigned short As[128 * 40];   // pitch 80B (16B aligned)
    __shared__ unsigned short Ws[128 * 40];
    const int tid  = threadIdx.x;
    const int lane = tid & 63;
    const int w    = tid >> 6;
    const int n    = lane & 15;
    const int quad = lane >> 4;
    const int bm   = blockIdx.x * 128;
    const int by   = blockIdx.y;              // 0..15
    const int half = by >> 3;
    const int ug32 = (by & 7) * 32;
    const unsigned short* Wb = Wbf + (size_t)half * 1024 * Kp;
    const float* biasp = half ? bb_ : bf_;

    f32x4 acc[2][8];
#pragma unroll
    for (int rt = 0; rt < 2; rt++)
#pragma unroll
        for (int ct = 0; ct < 8; ct++) acc[rt][ct] = (f32x4){0.f, 0.f, 0.f, 0.f};

    const int chunks = Kp >> 5;
    for (int kc = 0; kc < chunks; kc++) {
        const int k0 = kc * 32;
#pragma unroll
        for (int j = 0; j < 2; j++) {
            int idx = j * 256 + tid;
            int arow = idx >> 2, qq = idx & 3;
            int grow = bm + arow; if (grow >= M) grow = M - 1;
            *(uint4*)&As[arow * 40 + qq * 8] =
                *(const uint4*)(Abf + (size_t)grow * Kp + k0 + qq * 8);
            int cc = idx >> 2;
            int wrow = (cc >> 5) * 256 + ug32 + (cc & 31);   // gate=cc>>5, unit
            *(uint4*)&Ws[cc * 40 + qq * 8] =
                *(const uint4*)(Wb + (size_t)wrow * Kp + k0 + qq * 8);
        }
        __syncthreads();
        bf16x8 Aq[2], Bq[8];
#pragma unroll
        for (int rt = 0; rt < 2; rt++)
            Aq[rt] = *(const bf16x8*)&As[((w * 2 + rt) * 16 + n) * 40 + quad * 8];
#pragma unroll
        for (int ct = 0; ct < 8; ct++)
            Bq[ct] = *(const bf16x8*)&Ws[(ct * 16 + n) * 40 + quad * 8];
#pragma unroll
        for (int rt = 0; rt < 2; rt++)
#pragma unroll
            for (int ct = 0; ct < 8; ct++)
                acc[rt][ct] = __builtin_amdgcn_mfma_f32_16x16x32_bf16(
                    Aq[rt], Bq[ct], acc[rt][ct], 0, 0, 0);
        __syncthreads();
    }

#pragma unroll
    for (int s = 0; s < 2; s++) {
        const int uL = s * 16 + n;
        float b0 = biasp[ug32 + uL];
        float b1 = biasp[256 + ug32 + uL];
        float b2 = biasp[512 + ug32 + uL];
        float b3 = biasp[768 + ug32 + uL];
#pragma unroll
        for (int rt = 0; rt < 2; rt++) {
#pragma unroll
            for (int r = 0; r < 4; r++) {
                int row = bm + (w * 2 + rt) * 16 + quad * 4 + r;
                if (row >= M) continue;
                float4 o;
                o.x = acc[rt][0 + s][r] + b0;
                o.y = acc[rt][2 + s][r] + b1;
                o.z = acc[rt][4 + s][r] + b2;
                o.w = acc[rt][6 + s][r] + b3;
                *(float4*)(out + (size_t)row * 2048 + half * 1024 + (ug32 + uL) * 4) = o;
            }
        }
    }
}

// ---------------------------------------------------------------------------
// group barrier: 16 blocks, MONOTONIC counter, ALL RELAXED agent atomics.
// No acquire/release: every cross-block datum (h, counter) travels via
// coherence-point-bypassing atomics, so no cache maintenance is needed.
// __syncthreads drains each thread's h-stores (vmcnt) before arrival.
// ---------------------------------------------------------------------------
__device__ __forceinline__ void group_barrier(unsigned* cnt, unsigned target) {
    __syncthreads();
    if (threadIdx.x == 0) {
        __hip_atomic_fetch_add(cnt, 1u, __ATOMIC_RELAXED, __HIP_MEMORY_SCOPE_AGENT);
        while (__hip_atomic_load(cnt, __ATOMIC_RELAXED, __HIP_MEMORY_SCOPE_AGENT) < target)
            __builtin_amdgcn_s_sleep(1);
    }
    __syncthreads();
}

__device__ __forceinline__ const float* sen_xbase(
    const float* xw, const float* xw_head, int grow_e, int t)
{
    if (grow_e < 640)       return xw + ((size_t)grow_e * 30 + t) * 2048;
    else if (grow_e < 1280) return xw + ((size_t)(grow_e - 640) * 30 + 29 - t) * 2048 + 1024;
    else if (grow_e < 1344) return xw_head + ((size_t)(grow_e - 1280) * 15 + t) * 2048;
    else                    return xw_head + ((size_t)(grow_e - 1344) * 15 + 14 - t) * 2048 + 1024;
}

// ============================================================================
// lstm_sen: persistent BiLSTM, grid (16 unit-groups, 22 row-groups).
// Rows: 0..639 sen-fwd | 640..1279 sen-bwd | 1280..1343 head-f | 1344..1407 head-b.
// xw prefetched one step ahead (issued before the barrier wait).
// ============================================================================
__global__ __launch_bounds__(256, 2) void lstm_sen(
    const float* __restrict__ xw, const float* __restrict__ xw_head,
    const float* __restrict__ whh_f, const float* __restrict__ whh_b,
    unsigned short* hbA, unsigned short* hbB,
    float* __restrict__ sentences, float* __restrict__ headings,
    unsigned* bars)
{
    const int tid  = threadIdx.x;
    const int lane = tid & 63;
    const int w    = tid >> 6;
    const int n    = lane & 15;
    const int quad = lane >> 4;
    const int ug   = blockIdx.x;       // 0..15
    const int rg   = blockIdx.y;       // 0..21
    const int r0   = rg * 64;
    const int u0   = ug * 16;
    const bool bwd  = (rg >= 10 && rg < 20) || (rg == 21);
    const bool head = (rg >= 20);
    const float* whh = bwd ? whh_b : whh_f;
    unsigned* cnt = bars + rg * 16;    // 64B-separated counters
    const int tEnd = head ? 15 : 30;

    __shared__ float G[64][68];        // row pitch 272B (16B aligned)

    // Whh -> register B-frags. MFMA col cc=ct*16+n -> (unit uL=cc>>2, gate=cc&3);
    // W row = gate*256 + u0 + uL.
    bf16x8 Bf[4][8];
#pragma unroll
    for (int ct = 0; ct < 4; ct++) {
        const int c    = ct * 16 + n;
        const int grow = (c & 3) * 256 + u0 + (c >> 2);
        const float* wr = whh + (size_t)grow * 256;
#pragma unroll
        for (int ks = 0; ks < 8; ks++) {
            union { bf16x8 v; short s[8]; } tmp;
            const float* p = wr + ks * 32 + quad * 8;
#pragma unroll
            for (int j = 0; j < 8; j++) tmp.s[j] = (short)f2bf(p[j]);
            Bf[ct][ks] = tmp.v;
        }
    }

    float cr[4] = {0.f, 0.f, 0.f, 0.f};
    const int rr = tid >> 2;
    const int us = (tid & 3) * 4;             // local unit base
    const int grow_e = r0 + rr;

    // preload xw slice for t=0
    float4 xv[4];
    {
        const float4* xp = (const float4*)(sen_xbase(xw, xw_head, grow_e, 0)
                                           + (size_t)(u0 + us) * 4);
        xv[0] = xp[0]; xv[1] = xp[1]; xv[2] = xp[2]; xv[3] = xp[3];
    }

    for (int t = 0; t < tEnd; t++) {
        const unsigned short* hp = (t & 1) ? hbB : hbA;
        unsigned short*       hq = (t & 1) ? hbA : hbB;

        // ---- hidden GEMM (MFMA) ----
        {
            const unsigned long long* hrow =
                (const unsigned long long*)(hp + (size_t)(r0 + w * 16 + n) * 256);
            unsigned long long a0[8], a1[8];
#pragma unroll
            for (int ks = 0; ks < 8; ks++) {
                a0[ks] = __hip_atomic_load(hrow + ks * 8 + quad * 2,
                                           __ATOMIC_RELAXED, __HIP_MEMORY_SCOPE_AGENT);
                a1[ks] = __hip_atomic_load(hrow + ks * 8 + quad * 2 + 1,
                                           __ATOMIC_RELAXED, __HIP_MEMORY_SCOPE_AGENT);
            }
            f32x4 acc[4];
#pragma unroll
            for (int ct = 0; ct < 4; ct++) acc[ct] = (f32x4){0.f, 0.f, 0.f, 0.f};
#pragma unroll
            for (int ks = 0; ks < 8; ks++) {
                union { bf16x8 v; unsigned long long q[2]; } af;
                af.q[0] = a0[ks]; af.q[1] = a1[ks];
#pragma unroll
                for (int ct = 0; ct < 4; ct++)
                    acc[ct] = __builtin_amdgcn_mfma_f32_16x16x32_bf16(
                        af.v, Bf[ct][ks], acc[ct], 0, 0, 0);
            }
#pragma unroll
            for (int ct = 0; ct < 4; ct++)
#pragma unroll
                for (int r = 0; r < 4; r++)
                    G[w * 16 + quad * 4 + r][ct * 16 + n] = acc[ct][r];
        }
        __syncthreads();

        // ---- gate epilogue ----
        {
            float* fdst = nullptr;
            if (!head) {
                if (t == 29) fdst = sentences +
                    (size_t)(bwd ? grow_e - 640 : grow_e) * 512 + (bwd ? 256 : 0);
            } else {
                if (t == 14) fdst = headings +
                    (size_t)(grow_e - (bwd ? 1344 : 1280)) * 512 + (bwd ? 256 : 0);
            }
            const float4* Gp = (const float4*)&G[rr][us * 4];
            unsigned long long hpack = 0ull;
            float hout[4];
#pragma unroll
            for (int p = 0; p < 4; p++) {
                float4 gv = Gp[p];
                float4 xq = xv[p];
                float gi = gv.x + xq.x;
                float gf = gv.y + xq.y;
                float gg = gv.z + xq.z;
                float go = gv.w + xq.w;
                float cn = sigm(gf) * cr[p] + sigm(gi) * tanhf(gg);
                float hn = sigm(go) * tanhf(cn);
                cr[p] = cn; hout[p] = hn;
                hpack |= ((unsigned long long)f2bf(hn)) << (16 * p);
            }
            __hip_atomic_store((unsigned long long*)(hq + (size_t)grow_e * 256 + u0 + us),
                               hpack, __ATOMIC_RELAXED, __HIP_MEMORY_SCOPE_AGENT);
            if (fdst) *(float4*)(fdst + u0 + us) = *(float4*)hout;
        }

        if (t + 1 < tEnd) {
            // prefetch next step's xw BEFORE the barrier wait (h-independent)
            const float4* xp = (const float4*)(sen_xbase(xw, xw_head, grow_e, t + 1)
                                               + (size_t)(u0 + us) * 4);
            xv[0] = xp[0]; xv[1] = xp[1]; xv[2] = xp[2]; xv[3] = xp[3];
            group_barrier(cnt, 16u * (unsigned)(t + 1));
        }
    }
}

// ============================================================================
// lstm_doc: persistent BiLSTM over 64 docs x 10 steps. Grid (16, 2).
// ============================================================================
__global__ __launch_bounds__(256, 2) void lstm_doc(
    const float* __restrict__ xw,
    const float* __restrict__ whh_f, const float* __restrict__ whh_b,
    unsigned short* hbA, unsigned short* hbB,
    float* __restrict__ documents,
    unsigned* bars)
{
    const int tid  = threadIdx.x;
    const int lane = tid & 63;
    const int w    = tid >> 6;
    const int n    = lane & 15;
    const int quad = lane >> 4;
    const int ug   = blockIdx.x;       // 0..15
    const int rg   = blockIdx.y;       // 0..1
    const int r0   = rg * 64;
    const int u0   = ug * 16;
    const bool bwd = (rg == 1);
    const float* whh = bwd ? whh_b : whh_f;
    unsigned* cnt = bars + rg * 16;

    __shared__ float G[64][68];

    bf16x8 Bf[4][8];
#pragma unroll
    for (int ct = 0; ct < 4; ct++) {
        const int c    = ct * 16 + n;
        const int grow = (c & 3) * 256 + u0 + (c >> 2);
        const float* wr = whh + (size_t)grow * 256;
#pragma unroll
        for (int ks = 0; ks < 8; ks++) {
            union { bf16x8 v; short s[8]; } tmp;
            const float* p = wr + ks * 32 + quad * 8;
#pragma unroll
            for (int j = 0; j < 8; j++) tmp.s[j] = (short)f2bf(p[j]);
            Bf[ct][ks] = tmp.v;
        }
    }

    float cr[4] = {0.f, 0.f, 0.f, 0.f};
    const int rr = tid >> 2;
    const int us = (tid & 3) * 4;
    const int grow_e = r0 + rr;
    const int seq = rr;                        // doc index

    float4 xv[4];
    {
        const float* xb = !bwd ? xw + ((size_t)seq * 10 + 0) * 2048
                               : xw + ((size_t)seq * 10 + 9) * 2048 + 1024;
        const float4* xp = (const float4*)(xb + (size_t)(u0 + us) * 4);
        xv[0] = xp[0]; xv[1] = xp[1]; xv[2] = xp[2]; xv[3] = xp[3];
    }

    for (int t = 0; t < 10; t++) {
        const unsigned short* hp = (t & 1) ? hbB : hbA;
        unsigned short*       hq = (t & 1) ? hbA : hbB;
        const int dpos = !bwd ? t : 9 - t;
        const int doff = !bwd ? 0 : 256;

        {
            const unsigned long long* hrow =
                (const unsigned long long*)(hp + (size_t)(r0 + w * 16 + n) * 256);
            unsigned long long a0[8], a1[8];
#pragma unroll
            for (int ks = 0; ks < 8; ks++) {
                a0[ks] = __hip_atomic_load(hrow + ks * 8 + quad * 2,
                                           __ATOMIC_RELAXED, __HIP_MEMORY_SCOPE_AGENT);
                a1[ks] = __hip_atomic_load(hrow + ks * 8 + quad * 2 + 1,
                                           __ATOMIC_RELAXED, __HIP_MEMORY_SCOPE_AGENT);
            }
            f32x4 acc[4];
#pragma unroll
            for (int ct = 0; ct < 4; ct++) acc[ct] = (f32x4){0.f, 0.f, 0.f, 0.f};
#pragma unroll
            for (int ks = 0; ks < 8; ks++) {
                union { bf16x8 v; unsigned long long q[2]; } af;
                af.q[0] = a0[ks]; af.q[1] = a1[ks];
#pragma unroll
                for (int ct = 0; ct < 4; ct++)
                    acc[ct] = __builtin_amdgcn_mfma_f32_16x16x32_bf16(
                        af.v, Bf[ct][ks], acc[ct], 0, 0, 0);
            }
#pragma unroll
            for (int ct = 0; ct < 4; ct++)
#pragma unroll
                for (int r = 0; r < 4; r++)
                    G[w * 16 + quad * 4 + r][ct * 16 + n] = acc[ct][r];
        }
        __syncthreads();
        {
            const float4* Gp = (const float4*)&G[rr][us * 4];
            unsigned long long hpack = 0ull;
            float hout[4];
#pragma unroll
            for (int p = 0; p < 4; p++) {
                float4 gv = Gp[p];
                float gi = gv.x + xv[p].x;
                float gf = gv.y + xv[p].y;
                float gg = gv.z + xv[p].z;
                float go = gv.w + xv[p].w;
                float cn = sigm(gf) * cr[p] + sigm(gi) * tanhf(gg);
                float hn = sigm(go) * tanhf(cn);
                cr[p] = cn; hout[p] = hn;
                hpack |= ((unsigned long long)f2bf(hn)) << (16 * p);
            }
            __hip_atomic_store((unsigned long long*)(hq + (size_t)grow_e * 256 + u0 + us),
                               hpack, __ATOMIC_RELAXED, __HIP_MEMORY_SCOPE_AGENT);
            *(float4*)(documents + (size_t)(seq * 10 + dpos) * 512 + doff + u0 + us) =
                *(float4*)hout;
        }
        if (t < 9) {
            const float* xb = !bwd ? xw + ((size_t)seq * 10 + t + 1) * 2048
                                   : xw + ((size_t)seq * 10 + 8 - t) * 2048 + 1024;
            const float4* xp = (const float4*)(xb + (size_t)(u0 + us) * 4);
            xv[0] = xp[0]; xv[1] = xp[1]; xv[2] = xp[2]; xv[3] = xp[3];
            group_barrier(cnt, 16u * (unsigned)(t + 1));
        }
    }
}

// SourceBias: biasedBf[t] = bf16(tanh(sen[t] @ trans[u] + sb_bias[u]))
__global__ __launch_bounds__(256) void source_bias(
    const float* __restrict__ sentences, const int* __restrict__ urls,
    const float* __restrict__ trans, const float* __restrict__ sb_bias,
    unsigned* __restrict__ biasedBf)
{
    const int tkn = blockIdx.x;
    const int u = urls[tkn];
    const float2* Tm = (const float2*)(trans + (size_t)u * 512 * 512);
    __shared__ float sv[512];
    for (int i = threadIdx.x; i < 512; i += 256) sv[i] = sentences[(size_t)tkn * 512 + i];
    __syncthreads();
    const int e = threadIdx.x;               // column pair (2e, 2e+1)
    float ax = 0.f, ay = 0.f;
#pragma unroll 4
    for (int d = 0; d < 512; d++) {
        float s = sv[d];
        float2 tv = Tm[(size_t)d * 256 + e];
        ax += s * tv.x; ay += s * tv.y;
    }
    const float2 bv = ((const float2*)(sb_bias + (size_t)u * 512))[e];
    float x = tanhf(ax + bv.x), y = tanhf(ay + bv.y);
    biasedBf[(size_t)tkn * 256 + e] = (unsigned)f2bf(x) | ((unsigned)f2bf(y) << 16);
}

// v[b,d] = sum_e attn_W[d,e] * heading[b,e]; block per b
__global__ __launch_bounds__(256) void attn_v(
    const float* __restrict__ W, const float* __restrict__ headings,
    float* __restrict__ v)
{
    const int b = blockIdx.x;
    __shared__ float hh[512];
    for (int i = threadIdx.x; i < 512; i += 256) hh[i] = headings[(size_t)b * 512 + i];
    __syncthreads();
    for (int d = threadIdx.x; d < 512; d += 256) {
        float a = 0.f;
        const float* wr = W + (size_t)d * 512;
        for (int e = 0; e < 512; e++) a += wr[e] * hh[e];
        v[(size_t)b * 512 + d] = a;
    }
}

// scores -> softmax -> doc_rep -> both MLP heads; block per batch element
__global__ __launch_bounds__(256) void attn_heads(
    const float* __restrict__ documents, const float* __restrict__ v,
    const float* __restrict__ attn_b,
    const float* __restrict__ bW1, const float* __restrict__ bb1,
    const float* __restrict__ bW2, const float* __restrict__ bb2,
    const float* __restrict__ tW1, const float* __restrict__ tb1,
    const float* __restrict__ tW2, const float* __restrict__ tb2,
    float* __restrict__ out)
{
    const int b = blockIdx.x, tid = threadIdx.x;
    const int lane = tid & 63, wv_ = tid >> 6;
    __shared__ float vv[512], dr[512], h1s[256], t1s[256], sw[12], lg[5];
    for (int i = tid; i < 512; i += 256) vv[i] = v[(size_t)b * 512 + i];
    __syncthreads();
    for (int q = 0; q < 3; q++) {
        int s = q * 4 + wv_;
        float p = 0.f;
        if (s < 10) {
            const float* dp = documents + (size_t)(b * 10 + s) * 512;
            for (int d = lane; d < 512; d += 64) p += dp[d] * vv[d];
        }
#pragma unroll
        for (int off = 32; off > 0; off >>= 1) p += __shfl_down(p, off, 64);
        if (s < 10 && lane == 0) sw[s] = p + attn_b[0];
    }
    __syncthreads();
    if (tid == 0) {
        float mx = sw[0];
        for (int s = 1; s < 10; s++) mx = fmaxf(mx, sw[s]);
        float sum = 0.f;
        for (int s = 0; s < 10; s++) { sw[s] = expf(sw[s] - mx); sum += sw[s]; }
        for (int s = 0; s < 10; s++) sw[s] /= sum;
    }
    __syncthreads();
    for (int d = tid; d < 512; d += 256) {
        float a = 0.f;
#pragma unroll
        for (int s = 0; s < 10; s++) a += sw[s] * documents[(size_t)(b * 10 + s) * 512 + d];
        dr[d] = a;
    }
    __syncthreads();
    {
        float a = bb1[tid], a2 = tb1[tid];
        const float* w1 = bW1 + (size_t)tid * 512;
        const float* w2 = tW1 + (size_t)tid * 512;
        for (int k = 0; k < 512; k++) { float x = dr[k]; a += x * w1[k]; a2 += x * w2[k]; }
        h1s[tid] = tanhf(a); t1s[tid] = tanhf(a2);
    }
    __syncthreads();
    if (tid < 5) {
        float a = bb2[tid];
        const float* wp = bW2 + (size_t)tid * 256;
        for (int k = 0; k < 256; k++) a += h1s[k] * wp[k];
        lg[tid] = tanhf(a);
    }
    if (tid == 32) {
        float a = tb2[0];
        for (int k = 0; k < 256; k++) a += t1s[k] * tW2[k];
        out[320 + b] = 1.f / (1.f + expf(-tanhf(a)));
    }
    __syncthreads();
    if (tid == 0) {
        float mx = lg[0];
        for (int j = 1; j < 5; j++) mx = fmaxf(mx, lg[j]);
        float sum = 0.f, e[5];
        for (int j = 0; j < 5; j++) { e[j] = expf(lg[j] - mx); sum += e[j]; }
        for (int j = 0; j < 5; j++) out[b * 5 + j] = e[j] / sum;
    }
}

extern "C" void kernel_launch(void* const* d_in, const int* in_sizes, int n_in,
                              void* d_out, int out_size, void* d_ws, size_t ws_size,
                              hipStream_t stream)
{
    (void)in_sizes; (void)n_in; (void)out_size; (void)ws_size;
    const int*   input_ids = (const int*)d_in[0];
    const int*   urls      = (const int*)d_in[1];
    const int*   titles    = (const int*)d_in[2];
    const float* emb       = (const float*)d_in[3];
    const float* sen_wih_f = (const float*)d_in[4];
    const float* sen_whh_f = (const float*)d_in[5];
    const float* sen_b_f   = (const float*)d_in[6];
    const float* sen_wih_b = (const float*)d_in[7];
    const float* sen_whh_b = (const float*)d_in[8];
    const float* sen_b_b   = (const float*)d_in[9];
    const float* trans     = (const float*)d_in[10];
    const float* sb_bias   = (const float*)d_in[11];
    const float* doc_wih_f = (const float*)d_in[12];
    const float* doc_whh_f = (const float*)d_in[13];
    const float* doc_b_f   = (const float*)d_in[14];
    const float* doc_wih_b = (const float*)d_in[15];
    const float* doc_whh_b = (const float*)d_in[16];
    const float* doc_b_b   = (const float*)d_in[17];
    const float* attn_W    = (const float*)d_in[18];
    const float* attn_b    = (const float*)d_in[19];
    const float* bias_W1   = (const float*)d_in[20];
    const float* bias_b1   = (const float*)d_in[21];
    const float* bias_W2   = (const float*)d_in[22];
    const float* bias_b2   = (const float*)d_in[23];
    const float* truth_W1  = (const float*)d_in[24];
    const float* truth_b1  = (const float*)d_in[25];
    const float* truth_W2  = (const float*)d_in[26];
    const float* truth_b2  = (const float*)d_in[27];
    float* out = (float*)d_out;

    // ------------------------------------------------------------------
    // Workspace layout with lifetime overlays (offsets in FLOATS).
    // Slot A = xw_all [0 .. 41,287,680): live D2–D3. After D3 overlaid by
    //   biasedBf(+0), xw_doc(+163,840), documents(+1,474,560), vbuf(+1,802,240).
    // Slot B = Abf [41,287,680 .. +3,225,600): live D1–D2. After D2 overlaid by
    //   sentences(+0), headings(+327,680), hbA(+360,448), hbB(+540,672),
    //   hdA(+720,896), hdB(+737,280), bars(+753,664).
    // Slot C = Wsen [44,513,280 .. +327,680). Slot D = Wdoc [44,840,960 .. +524,288).
    // ------------------------------------------------------------------
    float* ws = (float*)d_ws;
    float* xw_all      = ws;
    float* xw_head     = xw_all + (size_t)19200 * 2048;
    unsigned* biasedBf = (unsigned*)(ws + 0);
    float* xw_doc      = ws + 163840;
    float* documents   = ws + 1474560;
    float* vbuf        = ws + 1802240;

    float* slotB       = ws + 41287680;
    unsigned* Abf      = (unsigned*)slotB;
    float* sentences   = slotB;
    float* headings    = slotB + 327680;
    unsigned short* hbA = (unsigned short*)(slotB + 360448);
    unsigned short* hbB = (unsigned short*)(slotB + 540672);
    unsigned short* hdA = (unsigned short*)(slotB + 720896);
    unsigned short* hdB = (unsigned short*)(slotB + 737280);
    unsigned* barsS    = (unsigned*)(slotB + 753664);   // 22 counters, 16-uint stride
    unsigned* barsD    = barsS + 22 * 16;               // 2 counters

    unsigned* Wsen     = (unsigned*)(ws + 44513280);
    unsigned* Wdoc     = (unsigned*)(ws + 44840960);

    dim3 blk(256);

    // D1: gather + bf16 casts
    prep_cast<<<dim3((N0 + N1 + N2 + 255) / 256), blk, 0, stream>>>(
        input_ids, titles, emb, sen_wih_f, sen_wih_b, doc_wih_f, doc_wih_b,
        Abf, Wsen, Wdoc);

    // D2: sentence+title input projection
    proj_mfma<<<dim3(158, 16), blk, 0, stream>>>(
        (const unsigned short*)Abf, 20160, 320,
        (const unsigned short*)Wsen, sen_b_f, sen_b_b, xw_all);

    // Zero-init h states + barrier counters (slot B dead after D2)
    hipMemsetAsync(hbA, 0, (size_t)1408 * 256 * 2, stream);
    hipMemsetAsync(hdA, 0, (size_t)128 * 256 * 2, stream);
    hipMemsetAsync(barsS, 0, (22 + 2) * 16 * sizeof(unsigned), stream);

    // D3: persistent sentence/heading BiLSTM
    lstm_sen<<<dim3(16, 22), blk, 0, stream>>>(
        xw_all, xw_head, sen_whh_f, sen_whh_b, hbA, hbB,
        sentences, headings, barsS);

    // D4: SourceBias
    source_bias<<<dim3(640), blk, 0, stream>>>(sentences, urls, trans, sb_bias, biasedBf);

    // D5: document input projection
    proj_mfma<<<dim3(5, 16), blk, 0, stream>>>(
        (const unsigned short*)biasedBf, 640, 512,
        (const unsigned short*)Wdoc, doc_b_f, doc_b_b, xw_doc);

    // D6: persistent document BiLSTM
    lstm_doc<<<dim3(16, 2), blk, 0, stream>>>(
        xw_doc, doc_whh_f, doc_whh_b, hdA, hdB, documents, barsD);

    // D7/D8: attention + heads
    attn_v<<<dim3(64), blk, 0, stream>>>(attn_W, headings, vbuf);
    attn_heads<<<dim3(64), blk, 0, stream>>>(documents, vbuf, attn_b,
                                             bias_W1, bias_b1, bias_W2, bias_b2,
                                             truth_W1, truth_b1, truth_W2, truth_b2,
                                             out);
}